// Round 10
// baseline (1542.590 us; speedup 1.0000x reference)
//
#include <hip/hip_runtime.h>
#include <hip/hip_cooperative_groups.h>
#include <math.h>

namespace cg = cooperative_groups;

#define NEG_SLOPE 0.2f
#define EPSV 1e-16f
#define NEG_HUGE -1e30f
#define CAP 64   // slots per node; deg ~ Poisson(16)+1, P(deg>63) ~ 1e-12

typedef short short8 __attribute__((ext_vector_type(8)));   // 8 bf16 (4 VGPRs)
typedef float f32x4 __attribute__((ext_vector_type(4)));
typedef unsigned short u16;

// ---------------- W pre-pack element (shared by coop + fallback paths) ------
__device__ __forceinline__ void wpack_elem(int idx,
        const float* __restrict__ W1l, const float* __restrict__ W1r,
        const float* __restrict__ W2l, const float* __restrict__ W2r,
        u16* __restrict__ w1hi, u16* __restrict__ w1lo,
        u16* __restrict__ w2hi, u16* __restrict__ w2lo) {
    const int T1 = 128 * 128;
    u16 *dhi, *dlo; const float *Wl, *Wr; int li;
    if (idx < T1) { dhi = w1hi; dlo = w1lo; Wl = W1l; Wr = W1r; li = idx; }
    else          { dhi = w2hi; dlo = w2lo; Wl = W2l; Wr = W2r; li = idx - T1; }
    const int j = li & 7, l = (li >> 3) & 63, t = (li >> 9) & 7, c = li >> 12;
    const int k = c * 32 + (l >> 4) * 8 + j;
    const int n = t * 16 + (l & 15);
    const float v = (n < 64) ? Wl[k * 64 + n] : Wr[k * 64 + (n - 64)];
    const unsigned u = __float_as_uint(v);
    dhi[li] = (u16)(u >> 16);
    const float hif = __uint_as_float(u & 0xffff0000u);
    dlo[li] = (u16)(__float_as_uint(v - hif) >> 16);
}

// ---------------- split-bf16 MFMA GEMM tile (no LDS) ------------------------
// wave w computes rows [tile*64+w*16,+16) x 128 cols (Wl|Wr concat).
// D = Ahi*Bhi + Ahi*Blo + Alo*Bhi (lo*lo dropped, ~2^-16 rel).
template <int K>
__device__ __forceinline__ void gemm_mfma_tile(const float* __restrict__ X,
                                               const u16* __restrict__ whi,
                                               const u16* __restrict__ wlo,
                                               float* __restrict__ xl,
                                               float* __restrict__ xr,
                                               int N, int tile) {
    const int lane = threadIdx.x & 63;
    const int w = threadIdx.x >> 6;
    const int rowbase = tile * 64 + w * 16;
    const int m = lane & 15, q = lane >> 4;
    int ar = rowbase + m; if (ar > N - 1) ar = N - 1;       // clamped read, masked write
    const float* arow = X + (size_t)ar * K + q * 8;
    f32x4 acc[8];
#pragma unroll
    for (int t = 0; t < 8; ++t) acc[t] = (f32x4){0.f, 0.f, 0.f, 0.f};
#pragma unroll
    for (int c = 0; c < K / 32; ++c) {
        const float4 f0 = *(const float4*)(arow + c * 32);
        const float4 f1 = *(const float4*)(arow + c * 32 + 4);
        const float fs[8] = {f0.x, f0.y, f0.z, f0.w, f1.x, f1.y, f1.z, f1.w};
        short8 ahi, alo;
#pragma unroll
        for (int j = 0; j < 8; ++j) {
            const unsigned u = __float_as_uint(fs[j]);
            ahi[j] = (short)(u >> 16);
            const float hif = __uint_as_float(u & 0xffff0000u);
            alo[j] = (short)(__float_as_uint(fs[j] - hif) >> 16);
        }
        const u16* bp = whi + ((size_t)(c * 8) * 64 + lane) * 8;
        const u16* bq = wlo + ((size_t)(c * 8) * 64 + lane) * 8;
#pragma unroll
        for (int t = 0; t < 8; ++t) {
            const short8 bhi = *(const short8*)(bp + t * 64 * 8);
            const short8 blo = *(const short8*)(bq + t * 64 * 8);
            acc[t] = __builtin_amdgcn_mfma_f32_16x16x32_bf16(ahi, bhi, acc[t], 0, 0, 0);
            acc[t] = __builtin_amdgcn_mfma_f32_16x16x32_bf16(ahi, blo, acc[t], 0, 0, 0);
            acc[t] = __builtin_amdgcn_mfma_f32_16x16x32_bf16(alo, bhi, acc[t], 0, 0, 0);
        }
    }
    // C/D: col = t*16 + (lane&15), row = rowbase + (lane>>4)*4 + r
#pragma unroll
    for (int t = 0; t < 8; ++t) {
        const int col = t * 16 + m;
        float* dstp = (col < 64) ? (xl + col) : (xr + col - 64);
#pragma unroll
        for (int r = 0; r < 4; ++r) {
            const int row = rowbase + q * 4 + r;
            if (row < N) dstp[(size_t)row * 64] = acc[t][r];
        }
    }
}

// ---------------- fused attention for one dst (one wave, 16 edges/iter) -----
// NOTE: xr/out NOT __restrict__ (layer-2 aliases both to d_out).
__device__ __forceinline__ void attn_node(const float* __restrict__ xl,
                                          const float* xr,
                                          const float* __restrict__ att,
                                          const int* __restrict__ cnt,
                                          const int* __restrict__ csrc,
                                          const float* __restrict__ bias,
                                          float* out,
                                          int N, int relu, int dst) {
    if (dst >= N) return;   // called from wave-uniform loop; no syncs inside
    const int lane = threadIdx.x & 63;
    const int g = lane >> 4;
    const int i = lane & 15;
    const float4 xrv = *(const float4*)(xr + (size_t)dst * 64 + i * 4);
    const float4 aw  = *(const float4*)(att + i * 4);
    const int deg = cnt[dst];
    const int sidx = csrc[(size_t)dst * CAP + ((lane < deg) ? lane : 0)];
    float l = 0.0f;
    float4 acc = {0.0f, 0.0f, 0.0f, 0.0f};
    for (int t = 0; t < deg; t += 16) {
        const int s0 = t + g, s1 = t + 4 + g, s2 = t + 8 + g, s3 = t + 12 + g;
        const bool v0 = s0 < deg, v1 = s1 < deg, v2 = s2 < deg, v3 = s3 < deg;
        const int src0 = __shfl(sidx, s0, 64);
        const int src1 = __shfl(sidx, s1, 64);
        const int src2 = __shfl(sidx, s2, 64);
        const int src3 = __shfl(sidx, s3, 64);
        const float4 va = *(const float4*)(xl + (size_t)src0 * 64 + i * 4);
        const float4 vb = *(const float4*)(xl + (size_t)src1 * 64 + i * 4);
        const float4 vc = *(const float4*)(xl + (size_t)src2 * 64 + i * 4);
        const float4 vd = *(const float4*)(xl + (size_t)src3 * 64 + i * 4);
        float t0, p0, p1, p2, p3;
        t0 = va.x + xrv.x; t0 = fmaxf(t0, NEG_SLOPE * t0); p0 = aw.x * t0;
        t0 = va.y + xrv.y; t0 = fmaxf(t0, NEG_SLOPE * t0); p0 = fmaf(aw.y, t0, p0);
        t0 = va.z + xrv.z; t0 = fmaxf(t0, NEG_SLOPE * t0); p0 = fmaf(aw.z, t0, p0);
        t0 = va.w + xrv.w; t0 = fmaxf(t0, NEG_SLOPE * t0); p0 = fmaf(aw.w, t0, p0);
        t0 = vb.x + xrv.x; t0 = fmaxf(t0, NEG_SLOPE * t0); p1 = aw.x * t0;
        t0 = vb.y + xrv.y; t0 = fmaxf(t0, NEG_SLOPE * t0); p1 = fmaf(aw.y, t0, p1);
        t0 = vb.z + xrv.z; t0 = fmaxf(t0, NEG_SLOPE * t0); p1 = fmaf(aw.z, t0, p1);
        t0 = vb.w + xrv.w; t0 = fmaxf(t0, NEG_SLOPE * t0); p1 = fmaf(aw.w, t0, p1);
        t0 = vc.x + xrv.x; t0 = fmaxf(t0, NEG_SLOPE * t0); p2 = aw.x * t0;
        t0 = vc.y + xrv.y; t0 = fmaxf(t0, NEG_SLOPE * t0); p2 = fmaf(aw.y, t0, p2);
        t0 = vc.z + xrv.z; t0 = fmaxf(t0, NEG_SLOPE * t0); p2 = fmaf(aw.z, t0, p2);
        t0 = vc.w + xrv.w; t0 = fmaxf(t0, NEG_SLOPE * t0); p2 = fmaf(aw.w, t0, p2);
        t0 = vd.x + xrv.x; t0 = fmaxf(t0, NEG_SLOPE * t0); p3 = aw.x * t0;
        t0 = vd.y + xrv.y; t0 = fmaxf(t0, NEG_SLOPE * t0); p3 = fmaf(aw.y, t0, p3);
        t0 = vd.z + xrv.z; t0 = fmaxf(t0, NEG_SLOPE * t0); p3 = fmaf(aw.z, t0, p3);
        t0 = vd.w + xrv.w; t0 = fmaxf(t0, NEG_SLOPE * t0); p3 = fmaf(aw.w, t0, p3);
        p0 += __shfl_xor(p0, 1, 64); p1 += __shfl_xor(p1, 1, 64);
        p2 += __shfl_xor(p2, 1, 64); p3 += __shfl_xor(p3, 1, 64);
        p0 += __shfl_xor(p0, 2, 64); p1 += __shfl_xor(p1, 2, 64);
        p2 += __shfl_xor(p2, 2, 64); p3 += __shfl_xor(p3, 2, 64);
        p0 += __shfl_xor(p0, 4, 64); p1 += __shfl_xor(p1, 4, 64);
        p2 += __shfl_xor(p2, 4, 64); p3 += __shfl_xor(p3, 4, 64);
        p0 += __shfl_xor(p0, 8, 64); p1 += __shfl_xor(p1, 8, 64);
        p2 += __shfl_xor(p2, 8, 64); p3 += __shfl_xor(p3, 8, 64);
        const float d0 = __expf(v0 ? p0 : NEG_HUGE);
        const float d1 = __expf(v1 ? p1 : NEG_HUGE);
        const float d2 = __expf(v2 ? p2 : NEG_HUGE);
        const float d3 = __expf(v3 ? p3 : NEG_HUGE);
        l += (d0 + d1) + (d2 + d3);
        acc.x = fmaf(d0, va.x, fmaf(d1, vb.x, fmaf(d2, vc.x, fmaf(d3, vd.x, acc.x))));
        acc.y = fmaf(d0, va.y, fmaf(d1, vb.y, fmaf(d2, vc.y, fmaf(d3, vd.y, acc.y))));
        acc.z = fmaf(d0, va.z, fmaf(d1, vb.z, fmaf(d2, vc.z, fmaf(d3, vd.z, acc.z))));
        acc.w = fmaf(d0, va.w, fmaf(d1, vb.w, fmaf(d2, vc.w, fmaf(d3, vd.w, acc.w))));
    }
#pragma unroll
    for (int o = 16; o <= 32; o <<= 1) {
        l     += __shfl_xor(l, o, 64);
        acc.x += __shfl_xor(acc.x, o, 64);
        acc.y += __shfl_xor(acc.y, o, 64);
        acc.z += __shfl_xor(acc.z, o, 64);
        acc.w += __shfl_xor(acc.w, o, 64);
    }
    if (g == 0) {
        const float4 bv = *(const float4*)(bias + i * 4);
        const float inv = 1.0f / (l + EPSV);
        float4 r;
        r.x = fmaf(acc.x, inv, bv.x);
        r.y = fmaf(acc.y, inv, bv.y);
        r.z = fmaf(acc.z, inv, bv.z);
        r.w = fmaf(acc.w, inv, bv.w);
        if (relu) {
            r.x = fmaxf(r.x, 0.0f); r.y = fmaxf(r.y, 0.0f);
            r.z = fmaxf(r.z, 0.0f); r.w = fmaxf(r.w, 0.0f);
        }
        *(float4*)(out + (size_t)dst * 64 + i * 4) = r;
    }
}

// ---------------- the whole model: ONE cooperative kernel -------------------
// R9 failure: occupancy-derived grid -> launch rejected -> zeros shipped.
// Fix: __launch_bounds__(256,6) guarantees >=6 blocks/CU by register
// accounting; grid is FIXED at 6*256 CUs = 1536 -> launch cannot be rejected.
__global__ __launch_bounds__(256, 6) void k_fused(
        const int* __restrict__ ei, int E, int ET, int N,
        int* __restrict__ cnt, int* __restrict__ csrc,
        u16* __restrict__ w1hi, u16* __restrict__ w1lo,
        u16* __restrict__ w2hi, u16* __restrict__ w2lo,
        const float* __restrict__ W1l, const float* __restrict__ W1r,
        const float* __restrict__ W2l, const float* __restrict__ W2r,
        const float* __restrict__ att1, const float* __restrict__ b1,
        const float* __restrict__ att2, const float* __restrict__ b2,
        const float* __restrict__ x, float* fout,
        float* __restrict__ buf1, float* __restrict__ buf2) {
    cg::grid_group grid = cg::this_grid();
    const int nb = gridDim.x;
    const int gt = blockIdx.x * 256 + threadIdx.x;
    const int G = nb * 256;
    const int tiles = (N + 63) / 64;

    // ---- phase 1: zero cnt + pack W into MFMA B-frag hi/lo bf16 ----
    for (int i = gt; i < N; i += G) cnt[i] = 0;
    for (int idx = gt; idx < 128 * 128 + 64 * 128; idx += G)
        wpack_elem(idx, W1l, W1r, W2l, W2r, w1hi, w1lo, w2hi, w2lo);
    __threadfence();
    grid.sync();

    // ---- phase 2: slot-CSR build (atomic/L2) || layer-1 MFMA gemm ----
    {
        const int GB = (nb > tiles + 256) ? tiles : (nb / 2);   // gemm blocks
        if ((int)blockIdx.x < GB) {
            for (int t = blockIdx.x; t < tiles; t += GB)
                gemm_mfma_tile<128>(x, w1hi, w1lo, fout, buf1, N, t);
        } else {
            const int base = (blockIdx.x - GB) * 256 + threadIdx.x;
            const int GC = (nb - GB) * 256;
            for (int e = base; e < ET; e += GC) {
                int src, dst;
                if (e < E) { src = ei[e]; dst = ei[E + e]; }
                else       { src = dst = e - E; }
                const int slot = atomicAdd(&cnt[dst], 1);
                csrc[(size_t)dst * CAP + slot] = src;
            }
        }
    }
    __threadfence();
    grid.sync();

    // ---- phase 3: layer-1 attention (xl=fout, xr=buf1) -> h in buf2 ----
    for (int d = blockIdx.x * 4 + (threadIdx.x >> 6); d < N; d += nb * 4)
        attn_node(fout, buf1, att1, cnt, csrc, b1, buf2, N, 1, d);
    __threadfence();
    grid.sync();

    // ---- phase 4: layer-2 gemm (reads buf2 -> xl=buf1, xr=fout) ----
    for (int t = blockIdx.x; t < tiles; t += nb)
        gemm_mfma_tile<64>(buf2, w2hi, w2lo, buf1, fout, N, t);
    __threadfence();
    grid.sync();

    // ---- phase 5: layer-2 attention (xl=buf1, xr=fout) -> fout ----
    // each wave reads only its own xr row then overwrites it; no hazard
    for (int d = blockIdx.x * 4 + (threadIdx.x >> 6); d < N; d += nb * 4)
        attn_node(buf1, fout, att2, cnt, csrc, b2, fout, N, 0, d);
}

// ---------------- fallback path kernels (R8 multi-dispatch, proven) ---------
__global__ __launch_bounds__(256) void k_wpack(
        const float* __restrict__ W1l, const float* __restrict__ W1r,
        const float* __restrict__ W2l, const float* __restrict__ W2r,
        u16* __restrict__ w1hi, u16* __restrict__ w1lo,
        u16* __restrict__ w2hi, u16* __restrict__ w2lo) {
    int idx = blockIdx.x * 256 + threadIdx.x;
    if (idx < 128 * 128 + 64 * 128)
        wpack_elem(idx, W1l, W1r, W2l, W2r, w1hi, w1lo, w2hi, w2lo);
}

template <int K>
__global__ __launch_bounds__(256) void k_hist_gemm(const int* __restrict__ ei, int E, int ET,
                                                   int* __restrict__ cnt,
                                                   int* __restrict__ csrc, int GH,
                                                   const float* __restrict__ X,
                                                   const u16* __restrict__ whi,
                                                   const u16* __restrict__ wlo,
                                                   float* __restrict__ xl,
                                                   float* __restrict__ xr, int N) {
    if ((int)blockIdx.x < GH) {
        const int gt = blockIdx.x * 256 + threadIdx.x;
        const int G = GH * 256;
        for (int e = gt; e < ET; e += G) {
            int src, dst;
            if (e < E) { src = ei[e]; dst = ei[E + e]; }
            else       { src = dst = e - E; }
            const int slot = atomicAdd(&cnt[dst], 1);
            csrc[(size_t)dst * CAP + slot] = src;
        }
    } else {
        gemm_mfma_tile<K>(X, whi, wlo, xl, xr, N, blockIdx.x - GH);
    }
}

template <int K>
__global__ __launch_bounds__(256) void k_gemm(const float* __restrict__ X,
                                              const u16* __restrict__ whi,
                                              const u16* __restrict__ wlo,
                                              float* __restrict__ xl,
                                              float* __restrict__ xr, int N) {
    gemm_mfma_tile<K>(X, whi, wlo, xl, xr, N, blockIdx.x);
}

__global__ __launch_bounds__(256) void k_attn(const float* __restrict__ xl,
                                              const float* xr,
                                              const float* __restrict__ att,
                                              const int* __restrict__ cnt,
                                              const int* __restrict__ csrc,
                                              const float* __restrict__ bias,
                                              float* out, int N, int relu) {
    attn_node(xl, xr, att, cnt, csrc, bias, out, N, relu,
              blockIdx.x * 4 + (threadIdx.x >> 6));
}

// ---------------- launch ----------------

extern "C" void kernel_launch(void* const* d_in, const int* in_sizes, int n_in,
                              void* d_out, int out_size, void* d_ws, size_t ws_size,
                              hipStream_t stream) {
    const float* x    = (const float*)d_in[0];
    const int*   ei   = (const int*)d_in[1];
    const float* W1l  = (const float*)d_in[2];
    const float* W1r  = (const float*)d_in[3];
    const float* att1 = (const float*)d_in[4];
    const float* b1   = (const float*)d_in[5];
    const float* W2l  = (const float*)d_in[6];
    const float* W2r  = (const float*)d_in[7];
    const float* att2 = (const float*)d_in[8];
    const float* b2   = (const float*)d_in[9];

    int N  = in_sizes[0] / 128;
    int E  = in_sizes[1] / 2;
    int ET = E + N;               // with self loops

    int* wsi   = (int*)d_ws;
    int* cnt   = wsi;                        // N (N%4==0 keeps alignment)
    int* csrc  = cnt + N;                    // N*CAP
    u16* w1hi  = (u16*)(csrc + (size_t)N * CAP);
    u16* w1lo  = w1hi + 16384;
    u16* w2hi  = w1lo + 16384;
    u16* w2lo  = w2hi + 8192;
    float* buf1 = (float*)(w2lo + 8192);     // N*64
    float* buf2 = buf1 + (size_t)N * 64;     // N*64
    float* fout = (float*)d_out;

    // grid = 6 blocks/CU * 256 CUs, guaranteed resident by __launch_bounds__(256,6)
    const int grid = 6 * 256;

    void* args[] = {(void*)&ei, (void*)&E, (void*)&ET, (void*)&N,
                    (void*)&cnt, (void*)&csrc,
                    (void*)&w1hi, (void*)&w1lo, (void*)&w2hi, (void*)&w2lo,
                    (void*)&W1l, (void*)&W1r, (void*)&W2l, (void*)&W2r,
                    (void*)&att1, (void*)&b1, (void*)&att2, (void*)&b2,
                    (void*)&x, (void*)&fout, (void*)&buf1, (void*)&buf2};
    hipError_t err = hipLaunchCooperativeKernel((const void*)k_fused, dim3(grid),
                                                dim3(256), args, 0, stream);
    if (err != hipSuccess) {
        // deterministic fallback: proven R8 multi-dispatch pipeline
        const dim3 b256(256);
        const int GH = 512;
        const int gGemm = (N + 63) / 64;
        const int gAttn = (N + 3) / 4;
        hipMemsetAsync(cnt, 0, (size_t)N * sizeof(int), stream);
        k_wpack<<<(128 * 128 + 64 * 128 + 255) / 256, b256, 0, stream>>>(
            W1l, W1r, W2l, W2r, w1hi, w1lo, w2hi, w2lo);
        k_hist_gemm<128><<<GH + gGemm, b256, 0, stream>>>(ei, E, ET, cnt, csrc, GH,
                                                          x, w1hi, w1lo, fout, buf1, N);
        k_attn<<<gAttn, b256, 0, stream>>>(fout, buf1, att1, cnt, csrc, b1, buf2, N, 1);
        k_gemm<64><<<gGemm, b256, 0, stream>>>(buf2, w2hi, w2lo, buf1, fout, N);
        k_attn<<<gAttn, b256, 0, stream>>>(buf1, fout, att2, cnt, csrc, b2, fout, N, 0);
    }
}

// Round 11
// 226.468 us; speedup vs baseline: 6.8115x; 6.8115x over previous
//
#include <hip/hip_runtime.h>
#include <math.h>

#define NEG_SLOPE 0.2f
#define EPSV 1e-16f
#define NEG_HUGE -1e30f
#define CAP 64   // slots per node; deg ~ Poisson(16)+1, P(deg>63) ~ 1e-12

typedef short short8 __attribute__((ext_vector_type(8)));   // 8 bf16 (4 VGPRs)
typedef float f32x4 __attribute__((ext_vector_type(4)));
typedef unsigned short u16;

// ---------------- W pre-pack + cnt zero (one dispatch) ----------------------
// fp32 [K,64]x2 -> MFMA B-frag hi/lo bf16; also zeroes cnt[N] (grid-stride).
__global__ __launch_bounds__(256) void k_wpack(
        const float* __restrict__ W1l, const float* __restrict__ W1r,
        const float* __restrict__ W2l, const float* __restrict__ W2r,
        u16* __restrict__ w1hi, u16* __restrict__ w1lo,
        u16* __restrict__ w2hi, u16* __restrict__ w2lo,
        int* __restrict__ cnt, int N) {
    const int idx = blockIdx.x * 256 + threadIdx.x;
    const int G = gridDim.x * 256;
    for (int i = idx; i < N; i += G) cnt[i] = 0;
    const int T1 = 128 * 128, T2 = 64 * 128;
    if (idx >= T1 + T2) return;
    u16 *dhi, *dlo; const float *Wl, *Wr; int li;
    if (idx < T1) { dhi = w1hi; dlo = w1lo; Wl = W1l; Wr = W1r; li = idx; }
    else          { dhi = w2hi; dlo = w2lo; Wl = W2l; Wr = W2r; li = idx - T1; }
    const int j = li & 7, l = (li >> 3) & 63, t = (li >> 9) & 7, c = li >> 12;
    const int k = c * 32 + (l >> 4) * 8 + j;
    const int n = t * 16 + (l & 15);
    const float v = (n < 64) ? Wl[k * 64 + n] : Wr[k * 64 + (n - 64)];
    const unsigned u = __float_as_uint(v);
    dhi[li] = (u16)(u >> 16);
    const float hif = __uint_as_float(u & 0xffff0000u);
    dlo[li] = (u16)(__float_as_uint(v - hif) >> 16);
}

// ---------------- split-bf16 MFMA GEMM tile (no LDS) ------------------------
// wave w computes rows [tile*64+w*16,+16) x 128 cols (Wl|Wr concat).
// D = Ahi*Bhi + Ahi*Blo + Alo*Bhi (lo*lo dropped, ~2^-16 rel).
template <int K>
__device__ __forceinline__ void gemm_mfma_tile(const float* __restrict__ X,
                                               const u16* __restrict__ whi,
                                               const u16* __restrict__ wlo,
                                               float* __restrict__ xl,
                                               float* __restrict__ xr,
                                               int N, int tile) {
    const int lane = threadIdx.x & 63;
    const int w = threadIdx.x >> 6;
    const int rowbase = tile * 64 + w * 16;
    const int m = lane & 15, q = lane >> 4;
    int ar = rowbase + m; if (ar > N - 1) ar = N - 1;       // clamped read, masked write
    const float* arow = X + (size_t)ar * K + q * 8;
    f32x4 acc[8];
#pragma unroll
    for (int t = 0; t < 8; ++t) acc[t] = (f32x4){0.f, 0.f, 0.f, 0.f};
#pragma unroll
    for (int c = 0; c < K / 32; ++c) {
        const float4 f0 = *(const float4*)(arow + c * 32);
        const float4 f1 = *(const float4*)(arow + c * 32 + 4);
        const float fs[8] = {f0.x, f0.y, f0.z, f0.w, f1.x, f1.y, f1.z, f1.w};
        short8 ahi, alo;
#pragma unroll
        for (int j = 0; j < 8; ++j) {
            const unsigned u = __float_as_uint(fs[j]);
            ahi[j] = (short)(u >> 16);
            const float hif = __uint_as_float(u & 0xffff0000u);
            alo[j] = (short)(__float_as_uint(fs[j] - hif) >> 16);
        }
        const u16* bp = whi + ((size_t)(c * 8) * 64 + lane) * 8;
        const u16* bq = wlo + ((size_t)(c * 8) * 64 + lane) * 8;
#pragma unroll
        for (int t = 0; t < 8; ++t) {
            const short8 bhi = *(const short8*)(bp + t * 64 * 8);
            const short8 blo = *(const short8*)(bq + t * 64 * 8);
            acc[t] = __builtin_amdgcn_mfma_f32_16x16x32_bf16(ahi, bhi, acc[t], 0, 0, 0);
            acc[t] = __builtin_amdgcn_mfma_f32_16x16x32_bf16(ahi, blo, acc[t], 0, 0, 0);
            acc[t] = __builtin_amdgcn_mfma_f32_16x16x32_bf16(alo, bhi, acc[t], 0, 0, 0);
        }
    }
    // C/D: col = t*16 + (lane&15), row = rowbase + (lane>>4)*4 + r
#pragma unroll
    for (int t = 0; t < 8; ++t) {
        const int col = t * 16 + m;
        float* dstp = (col < 64) ? (xl + col) : (xr + col - 64);
#pragma unroll
        for (int r = 0; r < 4; ++r) {
            const int row = rowbase + q * 4 + r;
            if (row < N) dstp[(size_t)row * 64] = acc[t][r];
        }
    }
}

// fused: blocks [0,GH) build the slot-CSR in ONE pass (atomic slot grab +
// u16 scatter into csrc[dst*CAP+slot]); the rest do the layer-1 MFMA gemm.
// (R4/R10 lessons: NO cooperative fusion -- grid.sync forces cross-XCD
// coherence traffic, 852 MB / 6x slowdown. Multi-dispatch + block-role
// fusion only.)
template <int K>
__global__ __launch_bounds__(256) void k_hist_gemm(const int* __restrict__ ei, int E, int ET,
                                                   int* __restrict__ cnt,
                                                   u16* __restrict__ csrc, int GH,
                                                   const float* __restrict__ X,
                                                   const u16* __restrict__ whi,
                                                   const u16* __restrict__ wlo,
                                                   float* __restrict__ xl,
                                                   float* __restrict__ xr, int N) {
    if ((int)blockIdx.x < GH) {
        const int gt = blockIdx.x * 256 + threadIdx.x;
        const int G = GH * 256;
        for (int e = gt; e < ET; e += G) {
            int src, dst;
            if (e < E) { src = ei[e]; dst = ei[E + e]; }
            else       { src = dst = e - E; }
            const int slot = atomicAdd(&cnt[dst], 1);
            csrc[(size_t)dst * CAP + slot] = (u16)src;   // src < N <= 65535
        }
    } else {
        gemm_mfma_tile<K>(X, whi, wlo, xl, xr, N, blockIdx.x - GH);
    }
}

template <int K>
__global__ __launch_bounds__(256) void k_gemm(const float* __restrict__ X,
                                              const u16* __restrict__ whi,
                                              const u16* __restrict__ wlo,
                                              float* __restrict__ xl,
                                              float* __restrict__ xr, int N) {
    gemm_mfma_tile<K>(X, whi, wlo, xl, xr, N, blockIdx.x);
}

// ---------------- fused attention (one wave per dst, 16 edges/iter) ---------
// deg<=CAP -> single 64-wide u16 index load; 4 independent float4 gathers in
// flight; no max-subtraction (logits bounded, |p|~<6); invalid slots exp->0.
// xr/out not __restrict__: layer 2 aliases both to d_out (per-wave row RMW).
__global__ __launch_bounds__(256) void k_attn(const float* __restrict__ xl,
                                              const float* xr,
                                              const float* __restrict__ att,
                                              const int* __restrict__ cnt,
                                              const u16* __restrict__ csrc,
                                              const float* __restrict__ bias,
                                              float* out, int N, int relu) {
    const int lane = threadIdx.x & 63;
    const int g = lane >> 4;
    const int i = lane & 15;
    const int dst = blockIdx.x * 4 + (threadIdx.x >> 6);
    if (dst >= N) return;
    const float4 xrv = *(const float4*)(xr + (size_t)dst * 64 + i * 4);
    const float4 aw  = *(const float4*)(att + i * 4);
    const int deg = cnt[dst];
    const int sidx = (int)csrc[(size_t)dst * CAP + ((lane < deg) ? lane : 0)];
    float l = 0.0f;
    float4 acc = {0.0f, 0.0f, 0.0f, 0.0f};
    for (int t = 0; t < deg; t += 16) {
        const int s0 = t + g, s1 = t + 4 + g, s2 = t + 8 + g, s3 = t + 12 + g;
        const bool v0 = s0 < deg, v1 = s1 < deg, v2 = s2 < deg, v3 = s3 < deg;
        const int src0 = __shfl(sidx, s0, 64);
        const int src1 = __shfl(sidx, s1, 64);
        const int src2 = __shfl(sidx, s2, 64);
        const int src3 = __shfl(sidx, s3, 64);
        const float4 va = *(const float4*)(xl + (size_t)src0 * 64 + i * 4);
        const float4 vb = *(const float4*)(xl + (size_t)src1 * 64 + i * 4);
        const float4 vc = *(const float4*)(xl + (size_t)src2 * 64 + i * 4);
        const float4 vd = *(const float4*)(xl + (size_t)src3 * 64 + i * 4);
        float t0, p0, p1, p2, p3;
        t0 = va.x + xrv.x; t0 = fmaxf(t0, NEG_SLOPE * t0); p0 = aw.x * t0;
        t0 = va.y + xrv.y; t0 = fmaxf(t0, NEG_SLOPE * t0); p0 = fmaf(aw.y, t0, p0);
        t0 = va.z + xrv.z; t0 = fmaxf(t0, NEG_SLOPE * t0); p0 = fmaf(aw.z, t0, p0);
        t0 = va.w + xrv.w; t0 = fmaxf(t0, NEG_SLOPE * t0); p0 = fmaf(aw.w, t0, p0);
        t0 = vb.x + xrv.x; t0 = fmaxf(t0, NEG_SLOPE * t0); p1 = aw.x * t0;
        t0 = vb.y + xrv.y; t0 = fmaxf(t0, NEG_SLOPE * t0); p1 = fmaf(aw.y, t0, p1);
        t0 = vb.z + xrv.z; t0 = fmaxf(t0, NEG_SLOPE * t0); p1 = fmaf(aw.z, t0, p1);
        t0 = vb.w + xrv.w; t0 = fmaxf(t0, NEG_SLOPE * t0); p1 = fmaf(aw.w, t0, p1);
        t0 = vc.x + xrv.x; t0 = fmaxf(t0, NEG_SLOPE * t0); p2 = aw.x * t0;
        t0 = vc.y + xrv.y; t0 = fmaxf(t0, NEG_SLOPE * t0); p2 = fmaf(aw.y, t0, p2);
        t0 = vc.z + xrv.z; t0 = fmaxf(t0, NEG_SLOPE * t0); p2 = fmaf(aw.z, t0, p2);
        t0 = vc.w + xrv.w; t0 = fmaxf(t0, NEG_SLOPE * t0); p2 = fmaf(aw.w, t0, p2);
        t0 = vd.x + xrv.x; t0 = fmaxf(t0, NEG_SLOPE * t0); p3 = aw.x * t0;
        t0 = vd.y + xrv.y; t0 = fmaxf(t0, NEG_SLOPE * t0); p3 = fmaf(aw.y, t0, p3);
        t0 = vd.z + xrv.z; t0 = fmaxf(t0, NEG_SLOPE * t0); p3 = fmaf(aw.z, t0, p3);
        t0 = vd.w + xrv.w; t0 = fmaxf(t0, NEG_SLOPE * t0); p3 = fmaf(aw.w, t0, p3);
        p0 += __shfl_xor(p0, 1, 64); p1 += __shfl_xor(p1, 1, 64);
        p2 += __shfl_xor(p2, 1, 64); p3 += __shfl_xor(p3, 1, 64);
        p0 += __shfl_xor(p0, 2, 64); p1 += __shfl_xor(p1, 2, 64);
        p2 += __shfl_xor(p2, 2, 64); p3 += __shfl_xor(p3, 2, 64);
        p0 += __shfl_xor(p0, 4, 64); p1 += __shfl_xor(p1, 4, 64);
        p2 += __shfl_xor(p2, 4, 64); p3 += __shfl_xor(p3, 4, 64);
        p0 += __shfl_xor(p0, 8, 64); p1 += __shfl_xor(p1, 8, 64);
        p2 += __shfl_xor(p2, 8, 64); p3 += __shfl_xor(p3, 8, 64);
        const float d0 = __expf(v0 ? p0 : NEG_HUGE);
        const float d1 = __expf(v1 ? p1 : NEG_HUGE);
        const float d2 = __expf(v2 ? p2 : NEG_HUGE);
        const float d3 = __expf(v3 ? p3 : NEG_HUGE);
        l += (d0 + d1) + (d2 + d3);
        acc.x = fmaf(d0, va.x, fmaf(d1, vb.x, fmaf(d2, vc.x, fmaf(d3, vd.x, acc.x))));
        acc.y = fmaf(d0, va.y, fmaf(d1, vb.y, fmaf(d2, vc.y, fmaf(d3, vd.y, acc.y))));
        acc.z = fmaf(d0, va.z, fmaf(d1, vb.z, fmaf(d2, vc.z, fmaf(d3, vd.z, acc.z))));
        acc.w = fmaf(d0, va.w, fmaf(d1, vb.w, fmaf(d2, vc.w, fmaf(d3, vd.w, acc.w))));
    }
    // merge the 4 groups (plain sums)
#pragma unroll
    for (int o = 16; o <= 32; o <<= 1) {
        l     += __shfl_xor(l, o, 64);
        acc.x += __shfl_xor(acc.x, o, 64);
        acc.y += __shfl_xor(acc.y, o, 64);
        acc.z += __shfl_xor(acc.z, o, 64);
        acc.w += __shfl_xor(acc.w, o, 64);
    }
    if (g == 0) {
        const float4 bv = *(const float4*)(bias + i * 4);
        const float inv = 1.0f / (l + EPSV);
        float4 r;
        r.x = fmaf(acc.x, inv, bv.x);
        r.y = fmaf(acc.y, inv, bv.y);
        r.z = fmaf(acc.z, inv, bv.z);
        r.w = fmaf(acc.w, inv, bv.w);
        if (relu) {
            r.x = fmaxf(r.x, 0.0f); r.y = fmaxf(r.y, 0.0f);
            r.z = fmaxf(r.z, 0.0f); r.w = fmaxf(r.w, 0.0f);
        }
        *(float4*)(out + (size_t)dst * 64 + i * 4) = r;
    }
}

// ---------------- launch ----------------

extern "C" void kernel_launch(void* const* d_in, const int* in_sizes, int n_in,
                              void* d_out, int out_size, void* d_ws, size_t ws_size,
                              hipStream_t stream) {
    const float* x    = (const float*)d_in[0];
    const int*   ei   = (const int*)d_in[1];
    const float* W1l  = (const float*)d_in[2];
    const float* W1r  = (const float*)d_in[3];
    const float* att1 = (const float*)d_in[4];
    const float* b1   = (const float*)d_in[5];
    const float* W2l  = (const float*)d_in[6];
    const float* W2r  = (const float*)d_in[7];
    const float* att2 = (const float*)d_in[8];
    const float* b2   = (const float*)d_in[9];

    const int N  = in_sizes[0] / 128;
    const int E  = in_sizes[1] / 2;
    const int ET = E + N;               // with self loops
    const int GH = 512;                 // slot-CSR builder blocks (co-resident w/ gemm)

    // ws: cnt | csrc(u16 slot array) | W packs | buf1 | buf2
    int* wsi   = (int*)d_ws;
    int* cnt   = wsi;                        // N ints
    u16* csrc  = (u16*)(cnt + N);            // N*CAP u16 (N*CAP even -> alignment ok)
    u16* w1hi  = csrc + (size_t)N * CAP;
    u16* w1lo  = w1hi + 16384;
    u16* w2hi  = w1lo + 16384;
    u16* w2lo  = w2hi + 8192;
    float* buf1 = (float*)(w2lo + 8192);     // N*64
    float* buf2 = buf1 + (size_t)N * 64;     // N*64
    float* fout = (float*)d_out;

    const dim3 b256(256);
    const int gGemm = (N + 63) / 64;
    const int gAttn = (N + 3) / 4;

    // ---- W pack + cnt zero (one dispatch) ----
    k_wpack<<<(128 * 128 + 64 * 128 + 255) / 256, b256, 0, stream>>>(
        W1l, W1r, W2l, W2r, w1hi, w1lo, w2hi, w2lo, cnt, N);

    // ---- slot-CSR build fused with layer-1 MFMA gemm (xl->d_out, xr->buf1) ----
    k_hist_gemm<128><<<GH + gGemm, b256, 0, stream>>>(ei, E, ET, cnt, csrc, GH,
                                                      x, w1hi, w1lo, fout, buf1, N);
    // ---- Layer 1 attention: h -> buf2 ----
    k_attn<<<gAttn, b256, 0, stream>>>(fout, buf1, att1, cnt, csrc, b1, buf2, N, 1);

    // ---- Layer 2: gemm reads buf2, xl->buf1, xr->d_out (both dead) ----
    k_gemm<64><<<gGemm, b256, 0, stream>>>(buf2, w2hi, w2lo, buf1, fout, N);
    // attn2 reads xr from d_out then overwrites d_out per-row (no cross-block hazard)
    k_attn<<<gAttn, b256, 0, stream>>>(buf1, fout, att2, cnt, csrc, b2, fout, N, 0);
}